// Round 5
// baseline (271.900 us; speedup 1.0000x reference)
//
#include <hip/hip_runtime.h>
#include <hip/hip_bf16.h>
#include <stdint.h>

#define MD   128
#define LBAS 256

// ws layout: NkFull fp32 (256x128) @0, Mbf bf16 (128x128) @131072
#define MBF_OFF 131072ull
#define WS_NEED (131072ull + 32768ull)

typedef __attribute__((ext_vector_type(8))) __bf16 bf16x8;
typedef __attribute__((ext_vector_type(4))) float floatx4;
typedef __attribute__((ext_vector_type(8))) unsigned short ushortx8;
typedef __attribute__((ext_vector_type(4))) unsigned short ushortx4;

__device__ __forceinline__ float bf2f(unsigned short u){
  union { unsigned int i; float f; } v; v.i = ((unsigned int)u) << 16; return v.f;
}
__device__ __forceinline__ unsigned short f2bf(float x){
  union { float f; unsigned int i; } v; v.f = x;
  unsigned int r = v.i + 0x7FFFu + ((v.i >> 16) & 1u);
  return (unsigned short)(r >> 16);
}
__device__ __forceinline__ int detect_f32(const void* Bbasis){
  return ((const unsigned int*)Bbasis)[0] == 0x3F800000u;   // cos(pi)^4 == 1.0f
}

// ================= K0: Nk table + M->bf16 =================
__global__ __launch_bounds__(256) void nk2_kernel(const void* __restrict__ Acoeff,
                                                  const void* __restrict__ Bbasis,
                                                  const void* __restrict__ Mmat,
                                                  float* __restrict__ NkFull,
                                                  unsigned short* __restrict__ Mbf){
  int gid = blockIdx.x * 256 + threadIdx.x;
  const int isf = detect_f32(Bbasis);
  if (gid < LBAS * MD){
    int idx = gid >> 7, j = gid & 127;
    float a, b;
    if (isf){ a = ((const float*)Acoeff)[j*LBAS+idx]; b = ((const float*)Bbasis)[idx*MD+j]; }
    else    { a = bf2f(((const unsigned short*)Acoeff)[j*LBAS+idx]);
              b = bf2f(((const unsigned short*)Bbasis)[idx*MD+j]); }
    NkFull[gid] = a * b;
  } else {
    int m = gid - LBAS * MD;
    if (m < MD * MD){
      Mbf[m] = isf ? f2bf(((const float*)Mmat)[m]) : ((const unsigned short*)Mmat)[m];
    }
  }
}

// ================= K1: fused pool(2^4) + GEMM + epilogue =================
// Changes vs 87us base:
//  - x1-range split in half per block: grid 900->1800 (sustained 4 blocks/CU;
//    one overlap slab per half, +6% fetch)
//  - prefetch ISSUED AFTER the last barrier of the iteration (post-barD,
//    overlapping epilogue) -> no __syncthreads vmcnt(0) drain between issue
//    and use; Ct is a separate buffer so the loop-wrap needs no barrier
//  - pool reads vectorized: 8 x ds_read_b128 (was 32 x ds_read_b32)
//  - prv history in regs; sNk (16x128) staged once; Ct coalesced epilogue
// LDS = 16896(S) + 8448(Ct) + 4352(Ab) + 8192(sNk) = 37888 B -> 4 blocks/CU.
__global__ __launch_bounds__(256, 4) void mega_kernel(const void* __restrict__ vec,
                                                      const float* __restrict__ NkFull,
                                                      const unsigned short* __restrict__ Mbf,
                                                      const void* __restrict__ Bbasis,
                                                      void* __restrict__ out){
  __shared__ __align__(16) float S[32 * 132];                  // staging (x2-pair sums)
  __shared__ __align__(16) float Ct[16 * 132];                 // MFMA output transpose
  __shared__ __align__(16) unsigned short Ab[16 * 136];        // A-tile (row 15 unused)
  __shared__ __align__(16) float sNk[16 * 128];                // j1 x j4 Nk rows

  // --- block decode: grid 1800 = 8 xcd * 225 slot; u = slot*2+(xcd&1) in [0,450)
  //     b = xcd>>1; s = u>>1 (w2,w3 index); h = u&1 (x1 half) ---
  const int xcd  = blockIdx.x & 7;
  const int slot = blockIdx.x >> 3;
  const int b    = xcd >> 1;
  const int u    = slot * 2 + (xcd & 1);
  const int s    = u >> 1;
  const int h    = u & 1;
  const int w3 = s / 15;
  const int w2 = s - w3 * 15;
  const int t  = threadIdx.x;
  const int isf = detect_f32(Bbasis);

  const int x1beg = h ? 8 : 0;
  const int x1end = h ? 16 : 9;      // slabs [0..9) and [8..16); windows 0..7 / 8..14

  const int wave = t >> 6, lane = t & 63;
  const int quad = lane >> 4, l16 = lane & 15;

  // vec strides (elems): b 8388608, x1 524288, x2 32768, x3 2048, x4 128
  const size_t vbase0 = (size_t)b * 8388608 + (size_t)w2 * 32768 + (size_t)w3 * 2048;

  // --- per-thread static offsets ---
  int offF[4];   // fp32: 4 float4-chunks
#pragma unroll
  for (int k = 0; k < 4; ++k){
    const int ci = k * 256 + t;          // 0..1023
    const int row = ci >> 5;             // x3sub*16 + x4
    offF[k] = (row >> 4) * 2048 + (row & 15) * 128 + (ci & 31) * 4;
  }
  int offB[2];   // bf16: 2 ushortx8-chunks
#pragma unroll
  for (int k = 0; k < 2; ++k){
    const int ci = k * 256 + t;          // 0..511
    const int row = ci >> 4;
    offB[k] = (row >> 4) * 2048 + (row & 15) * 128 + (ci & 15) * 8;
  }

  floatx4 pre[4][2];   // prefetch regs (bf16 path bit-casts into pre[0..1])

  // --- prefetch first slab ---
  if (isf){
    const float* vf = (const float*)vec + vbase0 + (size_t)x1beg * 524288;
#pragma unroll
    for (int k = 0; k < 4; ++k){
      pre[k][0] = *(const floatx4*)(vf + offF[k]);
      pre[k][1] = *(const floatx4*)(vf + offF[k] + 32768);
    }
  } else {
    const unsigned short* vh = (const unsigned short*)vec + vbase0 + (size_t)x1beg * 524288;
#pragma unroll
    for (int k = 0; k < 2; ++k){
      *(ushortx8*)&pre[k][0] = *(const ushortx8*)(vh + offB[k]);
      *(ushortx8*)&pre[k][1] = *(const ushortx8*)(vh + offB[k] + 32768);
    }
  }

  // --- M fragments -> registers (loop-invariant; 16 VGPRs; L2-hot source) ---
  bf16x8 mfr[2][4];
#pragma unroll
  for (int cc = 0; cc < 2; ++cc)
#pragma unroll
    for (int s4 = 0; s4 < 4; ++s4)
      *(ushortx8*)&mfr[cc][s4] =
          *(const ushortx8*)(Mbf + ((wave * 2 + cc) * 16 + l16) * 128 + s4 * 32 + quad * 8);

  // --- stage the 16 Nk rows (j1 x j4) once; L2-hot source ---
  {
    const int j2f = (w2 & 3), j3f = (w3 & 3);
#pragma unroll
    for (int k = 0; k < 2; ++k){
      const int ci = k * 256 + t;            // 0..511 float4 chunks
      const int row16 = ci >> 5, c4 = (ci & 31) * 4;
      const int j1 = row16 >> 2, j4 = row16 & 3;
      const int nkrow = ((j1 * 4 + j2f) * 4 + j3f) * 4 + j4;
      *(floatx4*)&sNk[row16 * 128 + c4] = *(const floatx4*)&NkFull[nkrow * 128 + c4];
    }
  }

  const int pw4 = t >> 4;            // pooling coords (t<240 active)
  const int pc8 = (t & 15) * 8;
  const int owner = (t < 240);
  float prv[8];                      // per-thread pooled history

  for (int s1 = x1beg; s1 < x1end; ++s1){
    // ---- regs -> S (x2-pair sum); implicit vmcnt wait on own prefetch ----
    if (isf){
#pragma unroll
      for (int k = 0; k < 4; ++k){
        const int ci = k * 256 + t;
        const int row = ci >> 5, c4 = (ci & 31) * 4;
        floatx4 sv;
#pragma unroll
        for (int q = 0; q < 4; ++q) sv[q] = pre[k][0][q] + pre[k][1][q];
        *(floatx4*)&S[row * 132 + c4] = sv;
      }
    } else {
#pragma unroll
      for (int k = 0; k < 2; ++k){
        const int ci = k * 256 + t;
        const int row = ci >> 4, c8 = (ci & 15) * 8;
        const ushortx8 a = *(const ushortx8*)&pre[k][0];
        const ushortx8 c = *(const ushortx8*)&pre[k][1];
#pragma unroll
        for (int q = 0; q < 8; ++q) S[row * 132 + c8 + q] = bf2f(a[q]) + bf2f(c[q]);
      }
    }
    __syncthreads();   // bar B: S ready (no loads in flight here)

    // ---- pool x3,x4 (2x2) vectorized + A-tile build; history in regs ----
    if (owner){
      const int p0 = pw4 * 132 + pc8;
      const floatx4 a0 = *(const floatx4*)&S[p0];
      const floatx4 a1 = *(const floatx4*)&S[p0 + 4];
      const floatx4 b0 = *(const floatx4*)&S[p0 + 132];
      const floatx4 b1 = *(const floatx4*)&S[p0 + 136];
      const floatx4 c0 = *(const floatx4*)&S[p0 + 16 * 132];
      const floatx4 c1 = *(const floatx4*)&S[p0 + 16 * 132 + 4];
      const floatx4 d0 = *(const floatx4*)&S[p0 + 17 * 132];
      const floatx4 d1 = *(const floatx4*)&S[p0 + 17 * 132 + 4];
      float cur[8];
      const floatx4 lo = ((a0 + b0) + (c0 + d0)) * 0.125f;
      const floatx4 hi = ((a1 + b1) + (c1 + d1)) * 0.125f;
#pragma unroll
      for (int e = 0; e < 4; ++e){ cur[e] = lo[e]; cur[4 + e] = hi[e]; }
      if (s1 > x1beg){
        ushortx8 av;
#pragma unroll
        for (int e = 0; e < 8; ++e) av[e] = f2bf((cur[e] + prv[e]) * 0.5f);
        *(ushortx8*)&Ab[pw4 * 136 + pc8] = av;
      }
#pragma unroll
      for (int e = 0; e < 8; ++e) prv[e] = cur[e];
    }
    __syncthreads();   // bar C: Ab ready; S reads done

    if (s1 > x1beg){
      // ---- MFMA: wave w -> col tiles {2w, 2w+1}; B from registers ----
      floatx4 acc[2];
      acc[0] = (floatx4){0.f,0.f,0.f,0.f};
      acc[1] = (floatx4){0.f,0.f,0.f,0.f};
#pragma unroll
      for (int s4 = 0; s4 < 4; ++s4){
        const bf16x8 af = *(const bf16x8*)&Ab[l16 * 136 + s4 * 32 + quad * 8];
#pragma unroll
        for (int cc = 0; cc < 2; ++cc){
          acc[cc] = __builtin_amdgcn_mfma_f32_16x16x32_bf16(af, mfr[cc][s4], acc[cc], 0, 0, 0);
        }
      }
      // ---- transpose via Ct (separate buffer) ----
#pragma unroll
      for (int cc = 0; cc < 2; ++cc)
#pragma unroll
        for (int reg = 0; reg < 4; ++reg)
          Ct[(quad * 4 + reg) * 132 + (wave * 2 + cc) * 16 + l16] = acc[cc][reg];
      __syncthreads();   // bar D: Ct ready (LAST barrier of the iteration)

      // ---- prefetch s1+1 AFTER the last barrier: stays in flight through
      //      the epilogue and the loop wrap; no vmcnt(0) drain before use ----
      if (s1 + 1 < x1end){
        if (isf){
          const float* vf = (const float*)vec + vbase0 + (size_t)(s1 + 1) * 524288;
#pragma unroll
          for (int k = 0; k < 4; ++k){
            pre[k][0] = *(const floatx4*)(vf + offF[k]);
            pre[k][1] = *(const floatx4*)(vf + offF[k] + 32768);
          }
        } else {
          const unsigned short* vh = (const unsigned short*)vec + vbase0 + (size_t)(s1 + 1) * 524288;
#pragma unroll
          for (int k = 0; k < 2; ++k){
            *(ushortx8*)&pre[k][0] = *(const ushortx8*)(vh + offB[k]);
            *(ushortx8*)&pre[k][1] = *(const ushortx8*)(vh + offB[k] + 32768);
          }
        }
      }

      // ---- epilogue: 15 rows x 512 B contiguous stores ----
      const int w1 = s1 - 1;
      const int j1sel = w1 & 3;
      const size_t outBase = ((size_t)(((b * 15 + w1) * 15 + w2) * 15 + w3)) * 15;
#pragma unroll
      for (int k = 0; k < 2; ++k){
        const int ci = k * 256 + t;
        if (ci < 480){
          const int row = ci >> 5, c4 = (ci & 31) * 4;
          const floatx4 v  = *(const floatx4*)&Ct[row * 132 + c4];
          const floatx4 nk = *(const floatx4*)&sNk[(j1sel * 4 + (row & 3)) * 128 + c4];
          floatx4 o;
#pragma unroll
          for (int e = 0; e < 4; ++e) o[e] = nk[e] - v[e];
          if (isf){
            *(floatx4*)((float*)out + (outBase + row) * 128 + c4) = o;
          } else {
            ushortx4 ob;
#pragma unroll
            for (int e = 0; e < 4; ++e) ob[e] = f2bf(o[e]);
            *(ushortx4*)((unsigned short*)out + (outBase + row) * 128 + c4) = ob;
          }
        }
      }
    } else {
      // ---- priming iteration: prefetch next slab (after barC, no barrier
      //      before its consumption at the next S-write) ----
      if (s1 + 1 < x1end){
        if (isf){
          const float* vf = (const float*)vec + vbase0 + (size_t)(s1 + 1) * 524288;
#pragma unroll
          for (int k = 0; k < 4; ++k){
            pre[k][0] = *(const floatx4*)(vf + offF[k]);
            pre[k][1] = *(const floatx4*)(vf + offF[k] + 32768);
          }
        } else {
          const unsigned short* vh = (const unsigned short*)vec + vbase0 + (size_t)(s1 + 1) * 524288;
#pragma unroll
          for (int k = 0; k < 2; ++k){
            *(ushortx8*)&pre[k][0] = *(const ushortx8*)(vh + offB[k]);
            *(ushortx8*)&pre[k][1] = *(const ushortx8*)(vh + offB[k] + 32768);
          }
        }
      }
    }
  }
}

extern "C" void kernel_launch(void* const* d_in, const int* in_sizes, int n_in,
                              void* d_out, int out_size, void* d_ws, size_t ws_size,
                              hipStream_t stream) {
  const void* vec = d_in[0];   // (4,16,16,16,16,128)
  const void* Mm  = d_in[1];   // (128,128)
  const void* Ac  = d_in[2];   // (128,256)
  const void* Bb  = d_in[3];   // (256,128)

  float* NkFull = (float*)d_ws;
  unsigned short* Mbf = (unsigned short*)((char*)d_ws + MBF_OFF);

  nk2_kernel<<<192, 256, 0, stream>>>(Ac, Bb, Mm, NkFull, Mbf);
  mega_kernel<<<1800, 256, 0, stream>>>(vec, NkFull, Mbf, Bb, d_out);
}

// Round 6
// 268.124 us; speedup vs baseline: 1.0141x; 1.0141x over previous
//
#include <hip/hip_runtime.h>
#include <hip/hip_bf16.h>
#include <stdint.h>

#define MD   128
#define LBAS 256

// ws layout: NkFull fp32 (256x128) @0, Mbf bf16 (128x128) @131072
#define MBF_OFF 131072ull
#define WS_NEED (131072ull + 32768ull)

typedef __attribute__((ext_vector_type(8))) __bf16 bf16x8;
typedef __attribute__((ext_vector_type(4))) float floatx4;
typedef __attribute__((ext_vector_type(8))) unsigned short ushortx8;
typedef __attribute__((ext_vector_type(4))) unsigned short ushortx4;

__device__ __forceinline__ float bf2f(unsigned short u){
  union { unsigned int i; float f; } v; v.i = ((unsigned int)u) << 16; return v.f;
}
__device__ __forceinline__ unsigned short f2bf(float x){
  union { float f; unsigned int i; } v; v.f = x;
  unsigned int r = v.i + 0x7FFFu + ((v.i >> 16) & 1u);
  return (unsigned short)(r >> 16);
}
__device__ __forceinline__ int detect_f32(const void* Bbasis){
  return ((const unsigned int*)Bbasis)[0] == 0x3F800000u;   // cos(pi)^4 == 1.0f
}

// ================= K0: Nk table + M->bf16 =================
__global__ __launch_bounds__(256) void nk2_kernel(const void* __restrict__ Acoeff,
                                                  const void* __restrict__ Bbasis,
                                                  const void* __restrict__ Mmat,
                                                  float* __restrict__ NkFull,
                                                  unsigned short* __restrict__ Mbf){
  int gid = blockIdx.x * 256 + threadIdx.x;
  const int isf = detect_f32(Bbasis);
  if (gid < LBAS * MD){
    int idx = gid >> 7, j = gid & 127;
    float a, b;
    if (isf){ a = ((const float*)Acoeff)[j*LBAS+idx]; b = ((const float*)Bbasis)[idx*MD+j]; }
    else    { a = bf2f(((const unsigned short*)Acoeff)[j*LBAS+idx]);
              b = bf2f(((const unsigned short*)Bbasis)[idx*MD+j]); }
    NkFull[gid] = a * b;
  } else {
    int m = gid - LBAS * MD;
    if (m < MD * MD){
      Mbf[m] = isf ? f2bf(((const float*)Mmat)[m]) : ((const unsigned short*)Mmat)[m];
    }
  }
}

// ================= K1: fused pool(2^4) + GEMM + epilogue =================
// Register-direct pooling WITHOUT cross-iteration prefetch (round-3 addressing,
// which passed correctness, minus the pre[8][2] spill): owner threads (t<240)
// load their own 2x2x2 window rows and accumulate on the fly, so the in-flight
// load registers die before MFMA/epilogue registers go live. No S staging ->
// 2 barriers/iter (was 3), no 16.5KB LDS round trip per iter.
// Exposed HBM latency per iter is hidden by 4 blocks/CU at staggered phases.
// LDS = 8448(Ct) + 4352(Ab) + 8192(sNk) = 20992 B; VGPR target <=128 (no spill).
__global__ __launch_bounds__(256, 4) void mega_kernel(const void* __restrict__ vec,
                                                      const float* __restrict__ NkFull,
                                                      const unsigned short* __restrict__ Mbf,
                                                      const void* __restrict__ Bbasis,
                                                      void* __restrict__ out){
  __shared__ __align__(16) float Ct[16 * 132];                 // MFMA output transpose
  __shared__ __align__(16) unsigned short Ab[16 * 136];        // A-tile (row 15 unused)
  __shared__ __align__(16) float sNk[16 * 128];                // j1 x j4 Nk rows

  // --- block decode: XCD-group same-b blocks (xcd = bid&7 -> {2b,2b+1}) ---
  const int xcd  = blockIdx.x & 7;
  const int slot = blockIdx.x >> 3;
  const int b    = xcd >> 1;
  const int s    = slot * 2 + (xcd & 1);
  if (s >= 225) return;
  const int w3 = s / 15;
  const int w2 = s - w3 * 15;
  const int t  = threadIdx.x;
  const int isf = detect_f32(Bbasis);

  const int wave = t >> 6, lane = t & 63;
  const int quad = lane >> 4, l16 = lane & 15;

  const int pw4   = t >> 4;            // window index along x4 (owner threads)
  const int pc8   = (t & 15) * 8;      // col base (8 floats)
  const int owner = (t < 240);

  // vec strides (elems): b 8388608, x1 524288, x2 32768, x3 2048, x4 128
  const size_t vbase0 = (size_t)b * 8388608 + (size_t)w2 * 32768 + (size_t)w3 * 2048;

  // 8 window rows: r = x2s*4 + x3s*2 + e4  (proven correct in round 3)
  int offR[8];
#pragma unroll
  for (int r = 0; r < 8; ++r){
    const int x2s = r >> 2, x3s = (r >> 1) & 1, e4 = r & 1;
    offR[r] = x2s * 32768 + x3s * 2048 + (pw4 + e4) * 128 + pc8;
  }

  // --- M fragments -> registers (loop-invariant; 16 VGPRs; L2-hot source) ---
  bf16x8 mfr[2][4];
#pragma unroll
  for (int cc = 0; cc < 2; ++cc)
#pragma unroll
    for (int s4 = 0; s4 < 4; ++s4)
      *(ushortx8*)&mfr[cc][s4] =
          *(const ushortx8*)(Mbf + ((wave * 2 + cc) * 16 + l16) * 128 + s4 * 32 + quad * 8);

  // --- stage the 16 Nk rows (j1 x j4) once; L2-hot source ---
  {
    const int j2f = (w2 & 3), j3f = (w3 & 3);
#pragma unroll
    for (int k = 0; k < 2; ++k){
      const int ci = k * 256 + t;            // 0..511 float4 chunks
      const int row16 = ci >> 5, c4 = (ci & 31) * 4;
      const int j1 = row16 >> 2, j4 = row16 & 3;
      const int nkrow = ((j1 * 4 + j2f) * 4 + j3f) * 4 + j4;
      *(floatx4*)&sNk[row16 * 128 + c4] = *(const floatx4*)&NkFull[nkrow * 128 + c4];
    }
  }

  float prv[8];                      // per-thread pooled history (in regs)

  for (int s1 = 0; s1 < 16; ++s1){
    // ---- register-direct pool: load 2x2x2 window rows, accumulate ----
    float cur[8];
    if (owner){
      if (isf){
        const float* vf = (const float*)vec + vbase0 + (size_t)s1 * 524288;
        floatx4 aLo = (floatx4){0.f,0.f,0.f,0.f};
        floatx4 aHi = (floatx4){0.f,0.f,0.f,0.f};
#pragma unroll
        for (int r = 0; r < 8; ++r){
          aLo += *(const floatx4*)(vf + offR[r]);
          aHi += *(const floatx4*)(vf + offR[r] + 4);
        }
        aLo *= 0.125f; aHi *= 0.125f;
#pragma unroll
        for (int e = 0; e < 4; ++e){ cur[e] = aLo[e]; cur[4 + e] = aHi[e]; }
      } else {
        const unsigned short* vh = (const unsigned short*)vec + vbase0 + (size_t)s1 * 524288;
        float av[8] = {0.f,0.f,0.f,0.f,0.f,0.f,0.f,0.f};
#pragma unroll
        for (int r = 0; r < 8; ++r){
          const ushortx8 u = *(const ushortx8*)(vh + offR[r]);
#pragma unroll
          for (int e = 0; e < 8; ++e) av[e] += bf2f(u[e]);
        }
#pragma unroll
        for (int e = 0; e < 8; ++e) cur[e] = av[e] * 0.125f;
      }
      // ---- A-tile build from (cur + prv)/2 ----
      if (s1 > 0){
        ushortx8 avv;
#pragma unroll
        for (int e = 0; e < 8; ++e) avv[e] = f2bf((cur[e] + prv[e]) * 0.5f);
        *(ushortx8*)&Ab[pw4 * 136 + pc8] = avv;
      }
#pragma unroll
      for (int e = 0; e < 8; ++e) prv[e] = cur[e];
    }
    __syncthreads();   // bar C: Ab ready; prev epilogue's Ct reads done

    if (s1 > 0){
      // ---- MFMA: wave w -> col tiles {2w, 2w+1}; B from registers ----
      floatx4 acc[2];
      acc[0] = (floatx4){0.f,0.f,0.f,0.f};
      acc[1] = (floatx4){0.f,0.f,0.f,0.f};
#pragma unroll
      for (int s4 = 0; s4 < 4; ++s4){
        const bf16x8 af = *(const bf16x8*)&Ab[l16 * 136 + s4 * 32 + quad * 8];
#pragma unroll
        for (int cc = 0; cc < 2; ++cc){
          acc[cc] = __builtin_amdgcn_mfma_f32_16x16x32_bf16(af, mfr[cc][s4], acc[cc], 0, 0, 0);
        }
      }
      // ---- transpose via Ct ----
#pragma unroll
      for (int cc = 0; cc < 2; ++cc)
#pragma unroll
        for (int reg = 0; reg < 4; ++reg)
          Ct[(quad * 4 + reg) * 132 + (wave * 2 + cc) * 16 + l16] = acc[cc][reg];
    }
    __syncthreads();   // bar D: Ct ready; Ab reads done (next Ab write safe)

    if (s1 > 0){
      // ---- epilogue: 15 rows x 512 B contiguous stores ----
      const int w1 = s1 - 1;
      const int j1sel = w1 & 3;
      const size_t outBase = ((size_t)(((b * 15 + w1) * 15 + w2) * 15 + w3)) * 15;
#pragma unroll
      for (int k = 0; k < 2; ++k){
        const int ci = k * 256 + t;
        if (ci < 480){
          const int row = ci >> 5, c4 = (ci & 31) * 4;
          const floatx4 v  = *(const floatx4*)&Ct[row * 132 + c4];
          const floatx4 nk = *(const floatx4*)&sNk[(j1sel * 4 + (row & 3)) * 128 + c4];
          floatx4 o;
#pragma unroll
          for (int e = 0; e < 4; ++e) o[e] = nk[e] - v[e];
          if (isf){
            *(floatx4*)((float*)out + (outBase + row) * 128 + c4) = o;
          } else {
            ushortx4 ob;
#pragma unroll
            for (int e = 0; e < 4; ++e) ob[e] = f2bf(o[e]);
            *(ushortx4*)((unsigned short*)out + (outBase + row) * 128 + c4) = ob;
          }
        }
      }
    }
  }
}

extern "C" void kernel_launch(void* const* d_in, const int* in_sizes, int n_in,
                              void* d_out, int out_size, void* d_ws, size_t ws_size,
                              hipStream_t stream) {
  const void* vec = d_in[0];   // (4,16,16,16,16,128)
  const void* Mm  = d_in[1];   // (128,128)
  const void* Ac  = d_in[2];   // (128,256)
  const void* Bb  = d_in[3];   // (256,128)

  float* NkFull = (float*)d_ws;
  unsigned short* Mbf = (unsigned short*)((char*)d_ws + MBF_OFF);

  nk2_kernel<<<192, 256, 0, stream>>>(Ac, Bb, Mm, NkFull, Mbf);
  mega_kernel<<<904, 256, 0, stream>>>(vec, NkFull, Mbf, Bb, d_out);
}

// Round 7
// 259.332 us; speedup vs baseline: 1.0485x; 1.0339x over previous
//
#include <hip/hip_runtime.h>
#include <hip/hip_bf16.h>
#include <stdint.h>

#define MD   128
#define LBAS 256

// ws layout: NkFull fp32 (256x128) @0, Mbf bf16 (128x128) @131072
#define MBF_OFF 131072ull
#define WS_NEED (131072ull + 32768ull)

typedef __attribute__((ext_vector_type(8))) __bf16 bf16x8;
typedef __attribute__((ext_vector_type(4))) float floatx4;
typedef __attribute__((ext_vector_type(8))) unsigned short ushortx8;
typedef __attribute__((ext_vector_type(4))) unsigned short ushortx4;

__device__ __forceinline__ float bf2f(unsigned short u){
  union { unsigned int i; float f; } v; v.i = ((unsigned int)u) << 16; return v.f;
}
__device__ __forceinline__ unsigned short f2bf(float x){
  union { float f; unsigned int i; } v; v.f = x;
  unsigned int r = v.i + 0x7FFFu + ((v.i >> 16) & 1u);
  return (unsigned short)(r >> 16);
}
__device__ __forceinline__ int detect_f32(const void* Bbasis){
  return ((const unsigned int*)Bbasis)[0] == 0x3F800000u;   // cos(pi)^4 == 1.0f
}

// ================= K0: Nk table + M->bf16 =================
__global__ __launch_bounds__(256) void nk2_kernel(const void* __restrict__ Acoeff,
                                                  const void* __restrict__ Bbasis,
                                                  const void* __restrict__ Mmat,
                                                  float* __restrict__ NkFull,
                                                  unsigned short* __restrict__ Mbf){
  int gid = blockIdx.x * 256 + threadIdx.x;
  const int isf = detect_f32(Bbasis);
  if (gid < LBAS * MD){
    int idx = gid >> 7, j = gid & 127;
    float a, b;
    if (isf){ a = ((const float*)Acoeff)[j*LBAS+idx]; b = ((const float*)Bbasis)[idx*MD+j]; }
    else    { a = bf2f(((const unsigned short*)Acoeff)[j*LBAS+idx]);
              b = bf2f(((const unsigned short*)Bbasis)[idx*MD+j]); }
    NkFull[gid] = a * b;
  } else {
    int m = gid - LBAS * MD;
    if (m < MD * MD){
      Mbf[m] = isf ? f2bf(((const float*)Mmat)[m]) : ((const unsigned short*)Mmat)[m];
    }
  }
}

// ================= K1: fused pool(2^4) + GEMM + epilogue =================
// R1 (87us) base with three verified-or-minimal deltas:
//  - SWAPPED MFMA operands: mfma(M_frag, A_frag, acc). Operand fragments have
//    identical per-lane layouts, so swapping transposes D: lane(quad,l16)
//    holds row w4=l16, cols j=(wave*2+cc)*16+quad*4+reg -> direct float4
//    stores. Kills Ct LDS round-trip AND the 4th barrier (r4's scalar-store
//    mistake avoided: 16B/lane vector stores).
//  - prv history in regs (verified r4/r6), pp LDS removed.
//  - sNk (16x128) staged once per block (verified r4/r5/r6).
// Prefetch timing IDENTICAL to R1 (S-write; prefetch; barB; pool; barC; MFMA).
// LDS = 16896(S) + 4352(Ab) + 8192(sNk) = 29440 B -> 5 blocks/CU.
__global__ __launch_bounds__(256, 4) void mega_kernel(const void* __restrict__ vec,
                                                      const float* __restrict__ NkFull,
                                                      const unsigned short* __restrict__ Mbf,
                                                      const void* __restrict__ Bbasis,
                                                      void* __restrict__ out){
  __shared__ __align__(16) float S[32 * 132];                  // staging (x2-pair sums)
  __shared__ __align__(16) unsigned short Ab[16 * 136];        // A-tile (row 15 zeroed)
  __shared__ __align__(16) float sNk[16 * 128];                // j1 x j4 Nk rows

  // --- block decode: XCD-group same-b blocks (xcd = bid&7 -> {2b,2b+1}) ---
  const int xcd  = blockIdx.x & 7;
  const int slot = blockIdx.x >> 3;
  const int b    = xcd >> 1;
  const int s    = slot * 2 + (xcd & 1);
  if (s >= 225) return;
  const int w3 = s / 15;
  const int w2 = s - w3 * 15;
  const int t  = threadIdx.x;
  const int isf = detect_f32(Bbasis);

  const int wave = t >> 6, lane = t & 63;
  const int quad = lane >> 4, l16 = lane & 15;

  // vec strides (elems): b 8388608, x1 524288, x2 32768, x3 2048, x4 128
  const size_t vbase0 = (size_t)b * 8388608 + (size_t)w2 * 32768 + (size_t)w3 * 2048;

  // --- per-thread static offsets ---
  int offF[4];   // fp32: 4 float4-chunks
#pragma unroll
  for (int k = 0; k < 4; ++k){
    const int ci = k * 256 + t;          // 0..1023
    const int row = ci >> 5;             // x3sub*16 + x4
    offF[k] = (row >> 4) * 2048 + (row & 15) * 128 + (ci & 31) * 4;
  }
  int offB[2];   // bf16: 2 ushortx8-chunks
#pragma unroll
  for (int k = 0; k < 2; ++k){
    const int ci = k * 256 + t;          // 0..511
    const int row = ci >> 4;
    offB[k] = (row >> 4) * 2048 + (row & 15) * 128 + (ci & 15) * 8;
  }

  floatx4 pre[4][2];   // prefetch regs (bf16 path bit-casts into pre[0..1])

  // --- prefetch x1 = 0 (issue HBM loads first) ---
  if (isf){
    const float* vf = (const float*)vec + vbase0;
#pragma unroll
    for (int k = 0; k < 4; ++k){
      pre[k][0] = *(const floatx4*)(vf + offF[k]);
      pre[k][1] = *(const floatx4*)(vf + offF[k] + 32768);
    }
  } else {
    const unsigned short* vh = (const unsigned short*)vec + vbase0;
#pragma unroll
    for (int k = 0; k < 2; ++k){
      *(ushortx8*)&pre[k][0] = *(const ushortx8*)(vh + offB[k]);
      *(ushortx8*)&pre[k][1] = *(const ushortx8*)(vh + offB[k] + 32768);
    }
  }

  // --- M fragments -> registers (loop-invariant; 16 VGPRs; L2-hot source) ---
  bf16x8 mfr[2][4];
#pragma unroll
  for (int cc = 0; cc < 2; ++cc)
#pragma unroll
    for (int s4 = 0; s4 < 4; ++s4)
      *(ushortx8*)&mfr[cc][s4] =
          *(const ushortx8*)(Mbf + ((wave * 2 + cc) * 16 + l16) * 128 + s4 * 32 + quad * 8);

  // --- stage the 16 Nk rows (j1 x j4) once; zero Ab row 15 ---
  {
    const int j2f = (w2 & 3), j3f = (w3 & 3);
#pragma unroll
    for (int k = 0; k < 2; ++k){
      const int ci = k * 256 + t;            // 0..511 float4 chunks
      const int row16 = ci >> 5, c4 = (ci & 31) * 4;
      const int j1 = row16 >> 2, j4 = row16 & 3;
      const int nkrow = ((j1 * 4 + j2f) * 4 + j3f) * 4 + j4;
      *(floatx4*)&sNk[row16 * 128 + c4] = *(const floatx4*)&NkFull[nkrow * 128 + c4];
    }
    if (t >= 240){                            // zero A-tile row 15 (read by MFMA, col 15 of D discarded)
      const ushortx8 z = (ushortx8){0,0,0,0,0,0,0,0};
      *(ushortx8*)&Ab[15 * 136 + (t & 15) * 8] = z;
    }
  }

  const int pw4 = t >> 4;            // pooling coords (t<240 active)
  const int pc8 = (t & 15) * 8;
  const int owner = (t < 240);
  float prv[8];                      // per-thread pooled history (in regs)

  for (int x1 = 0; x1 < 16; ++x1){
    // ---- regs -> S (x2-pair sum); implicit vmcnt wait on own prefetch ----
    if (isf){
#pragma unroll
      for (int k = 0; k < 4; ++k){
        const int ci = k * 256 + t;
        const int row = ci >> 5, c4 = (ci & 31) * 4;
        floatx4 sv;
#pragma unroll
        for (int q = 0; q < 4; ++q) sv[q] = pre[k][0][q] + pre[k][1][q];
        *(floatx4*)&S[row * 132 + c4] = sv;
      }
    } else {
#pragma unroll
      for (int k = 0; k < 2; ++k){
        const int ci = k * 256 + t;
        const int row = ci >> 4, c8 = (ci & 15) * 8;
        const ushortx8 a = *(const ushortx8*)&pre[k][0];
        const ushortx8 c = *(const ushortx8*)&pre[k][1];
#pragma unroll
        for (int q = 0; q < 8; ++q) S[row * 132 + c8 + q] = bf2f(a[q]) + bf2f(c[q]);
      }
    }

    // ---- prefetch x1+1 (same placement as the 87us R1 base) ----
    if (x1 < 15){
      if (isf){
        const float* vf = (const float*)vec + vbase0 + (size_t)(x1 + 1) * 524288;
#pragma unroll
        for (int k = 0; k < 4; ++k){
          pre[k][0] = *(const floatx4*)(vf + offF[k]);
          pre[k][1] = *(const floatx4*)(vf + offF[k] + 32768);
        }
      } else {
        const unsigned short* vh = (const unsigned short*)vec + vbase0 + (size_t)(x1 + 1) * 524288;
#pragma unroll
        for (int k = 0; k < 2; ++k){
          *(ushortx8*)&pre[k][0] = *(const ushortx8*)(vh + offB[k]);
          *(ushortx8*)&pre[k][1] = *(const ushortx8*)(vh + offB[k] + 32768);
        }
      }
    }
    __syncthreads();   // bar B: S ready

    // ---- pool x3,x4 (2x2) vectorized + A-tile build; history in regs ----
    if (owner){
      const int p0 = pw4 * 132 + pc8;
      const floatx4 a0 = *(const floatx4*)&S[p0];
      const floatx4 a1 = *(const floatx4*)&S[p0 + 4];
      const floatx4 b0 = *(const floatx4*)&S[p0 + 132];
      const floatx4 b1 = *(const floatx4*)&S[p0 + 136];
      const floatx4 c0 = *(const floatx4*)&S[p0 + 16 * 132];
      const floatx4 c1 = *(const floatx4*)&S[p0 + 16 * 132 + 4];
      const floatx4 d0 = *(const floatx4*)&S[p0 + 17 * 132];
      const floatx4 d1 = *(const floatx4*)&S[p0 + 17 * 132 + 4];
      float cur[8];
      const floatx4 lo = ((a0 + b0) + (c0 + d0)) * 0.125f;
      const floatx4 hi = ((a1 + b1) + (c1 + d1)) * 0.125f;
#pragma unroll
      for (int e = 0; e < 4; ++e){ cur[e] = lo[e]; cur[4 + e] = hi[e]; }
      if (x1 > 0){
        ushortx8 av;
#pragma unroll
        for (int e = 0; e < 8; ++e) av[e] = f2bf((cur[e] + prv[e]) * 0.5f);
        *(ushortx8*)&Ab[pw4 * 136 + pc8] = av;
      }
#pragma unroll
      for (int e = 0; e < 8; ++e) prv[e] = cur[e];
    }
    __syncthreads();   // bar C: Ab ready; S reads done; prev MFMA's Ab reads done

    if (x1 > 0){
      // ---- MFMA, SWAPPED operands: acc = mfma(M_frag, A_frag, acc) ----
      // D: row(w4)=l16, col(j)=(wave*2+cc)*16 + quad*4 + reg
      floatx4 acc[2];
      acc[0] = (floatx4){0.f,0.f,0.f,0.f};
      acc[1] = (floatx4){0.f,0.f,0.f,0.f};
#pragma unroll
      for (int s4 = 0; s4 < 4; ++s4){
        const bf16x8 af = *(const bf16x8*)&Ab[l16 * 136 + s4 * 32 + quad * 8];
#pragma unroll
        for (int cc = 0; cc < 2; ++cc){
          acc[cc] = __builtin_amdgcn_mfma_f32_16x16x32_bf16(mfr[cc][s4], af, acc[cc], 0, 0, 0);
        }
      }

      // ---- direct epilogue: float4 per (cc), row l16 (skip 15) ----
      if (l16 < 15){
        const int w1 = x1 - 1;
        const int j1sel = w1 & 3;
        const size_t outBase = ((size_t)(((b * 15 + w1) * 15 + w2) * 15 + w3)) * 15;
        const size_t rowOff = (outBase + l16) * 128;
        const int nkRow = (j1sel * 4 + (l16 & 3)) * 128;
#pragma unroll
        for (int cc = 0; cc < 2; ++cc){
          const int col = (wave * 2 + cc) * 16 + quad * 4;
          const floatx4 nk = *(const floatx4*)&sNk[nkRow + col];
          floatx4 o;
#pragma unroll
          for (int e = 0; e < 4; ++e) o[e] = nk[e] - acc[cc][e];
          if (isf){
            *(floatx4*)((float*)out + rowOff + col) = o;
          } else {
            ushortx4 ob;
#pragma unroll
            for (int e = 0; e < 4; ++e) ob[e] = f2bf(o[e]);
            *(ushortx4*)((unsigned short*)out + rowOff + col) = ob;
          }
        }
      }
    }
  }
}

extern "C" void kernel_launch(void* const* d_in, const int* in_sizes, int n_in,
                              void* d_out, int out_size, void* d_ws, size_t ws_size,
                              hipStream_t stream) {
  const void* vec = d_in[0];   // (4,16,16,16,16,128)
  const void* Mm  = d_in[1];   // (128,128)
  const void* Ac  = d_in[2];   // (128,256)
  const void* Bb  = d_in[3];   // (256,128)

  float* NkFull = (float*)d_ws;
  unsigned short* Mbf = (unsigned short*)((char*)d_ws + MBF_OFF);

  nk2_kernel<<<192, 256, 0, stream>>>(Ac, Bb, Mm, NkFull, Mbf);
  mega_kernel<<<904, 256, 0, stream>>>(vec, NkFull, Mbf, Bb, d_out);
}